// Round 6
// baseline (996.979 us; speedup 1.0000x reference)
//
#include <hip/hip_runtime.h>

// Problem constants (match reference setup_inputs)
#define NP 50000     // P: rows of HG_pu / rows of x,e,out
#define NU 100000    // U: rows of HG_up (intermediate y)
#define NNZ_C 1600000
#define DIM 128
#define NR_TOT (NU + NP)          // combined row space: [0,NU)=up, [NU,NU+NP)=pu
#define KB 6                      // rows per bucket = 64
#define NB ((NR_TOT + 63) / 64)   // 2344 buckets

// round-to-nearest bf16x2 pack: a -> low 16, b -> high 16
__device__ inline unsigned pack_bf16x2(float a, float b) {
    unsigned ia = __float_as_uint(a), ib = __float_as_uint(b);
    ia = (ia + 0x7FFFu + ((ia >> 16) & 1u)) >> 16;
    ib = (ib + 0x7FFFu + ((ib >> 16) & 1u)) >> 16;
    return ia | (ib << 16);
}

// x (fp32 [NP,128]) -> xh (bf16x2 words, 64 per row)
__global__ void cvt_bf16_kernel(const float* __restrict__ x,
                                unsigned* __restrict__ xh, int nwords) {
    int i = blockIdx.x * blockDim.x + threadIdx.x;
    if (i >= nwords) return;
    float2 v = ((const float2*)x)[i];
    xh[i] = pack_bf16x2(v.x, v.y);
}

// ---------------------------------------------------------------------------
// Combined CSR build over both matrices.
// ---------------------------------------------------------------------------

__global__ void hist_kernel(const int* __restrict__ rows_up,
                            const int* __restrict__ rows_pu,
                            int* __restrict__ counts) {
    int i = blockIdx.x * blockDim.x + threadIdx.x;
    if (i >= 2 * NNZ_C) return;
    int r = (i < NNZ_C) ? rows_up[i] : (NU + rows_pu[i - NNZ_C]);
    atomicAdd(&counts[r], 1);
}

// Phase 1: per-block (1024-element chunk) tree reduction -> partials[block]
__global__ void block_sum_kernel(const int* __restrict__ counts,
                                 int* __restrict__ partials, int n) {
    __shared__ int lds[1024];
    int i = blockIdx.x * 1024 + threadIdx.x;
    lds[threadIdx.x] = (i < n) ? counts[i] : 0;
    __syncthreads();
    for (int s = 512; s > 0; s >>= 1) {
        if (threadIdx.x < s) lds[threadIdx.x] += lds[threadIdx.x + s];
        __syncthreads();
    }
    if (threadIdx.x == 0) partials[blockIdx.x] = lds[0];
}

// Phase 2: single 256-thread block scans the <=256 partials (exclusive).
__global__ void scan_partials_kernel(const int* __restrict__ partials,
                                     int* __restrict__ base, int nb) {
    __shared__ int lds[256];
    int v = (threadIdx.x < nb) ? partials[threadIdx.x] : 0;
    lds[threadIdx.x] = v;
    __syncthreads();
    for (int off = 1; off < 256; off <<= 1) {
        int t = (threadIdx.x >= (unsigned)off) ? lds[threadIdx.x - off] : 0;
        __syncthreads();
        lds[threadIdx.x] += t;
        __syncthreads();
    }
    if (threadIdx.x < nb) base[threadIdx.x] = lds[threadIdx.x] - v;
}

// Phase 3: per-block local scan + block base -> row_ptr.
__global__ void final_scan_kernel(const int* __restrict__ counts,
                                  const int* __restrict__ base,
                                  int* __restrict__ row_ptr, int n) {
    __shared__ int lds[1024];
    int i = blockIdx.x * 1024 + threadIdx.x;
    int v = (i < n) ? counts[i] : 0;
    lds[threadIdx.x] = v;
    __syncthreads();
    for (int off = 1; off < 1024; off <<= 1) {
        int t = (threadIdx.x >= (unsigned)off) ? lds[threadIdx.x - off] : 0;
        __syncthreads();
        lds[threadIdx.x] += t;
        __syncthreads();
    }
    int excl = base[blockIdx.x] + lds[threadIdx.x] - v;
    if (i < n) {
        row_ptr[i] = excl;
        if (i == n - 1) row_ptr[n] = excl + v;
    }
}

// Bucket cursors start at the bucket's final CSR offset, so bucket regions in
// the staging array coincide with the final packed subranges.
__global__ void bucket_cursor_init_kernel(const int* __restrict__ row_ptr,
                                          int* __restrict__ bcur) {
    int b = blockIdx.x * blockDim.x + threadIdx.x;
    if (b < NB) bcur[b] = row_ptr[b << KB];
}

// Phase A: scatter items into per-bucket append regions. Active write window
// = NB lines (~150 KB) -> stays L2-resident, lines fill front-to-back.
// payload u32 = col<<15 | bf16bits(val)  (vals in [0,1] => bits < 2^15).
__global__ void bucket_scatter_kernel(const float* __restrict__ vals_up,
                                      const float* __restrict__ vals_pu,
                                      const int* __restrict__ rows_up,
                                      const int* __restrict__ rows_pu,
                                      const int* __restrict__ cols_up,
                                      const int* __restrict__ cols_pu,
                                      int* __restrict__ bcur,
                                      unsigned* __restrict__ bpacked,
                                      unsigned char* __restrict__ brow) {
    int i = blockIdx.x * blockDim.x + threadIdx.x;
    if (i >= 2 * NNZ_C) return;
    int r, c; float v;
    if (i < NNZ_C) { r = rows_up[i]; c = cols_up[i]; v = vals_up[i]; }
    else { int k = i - NNZ_C; r = NU + rows_pu[k]; c = cols_pu[k]; v = vals_pu[k]; }
    int pos = atomicAdd(&bcur[r >> KB], 1);
    unsigned vb = __float_as_uint(v);
    unsigned vr = (vb + 0x7FFFu + ((vb >> 16) & 1u)) >> 16;   // bf16 bits, sign=0
    bpacked[pos] = ((unsigned)c << 15) | vr;
    brow[pos] = (unsigned char)(r & 63);
}

// Phase B: one block per bucket; place items at final CSR positions via LDS
// row cursors. Write window = bucket's contiguous ~4-8 KB -> L1-resident.
__global__ void bucket_finalize_kernel(const int* __restrict__ row_ptr,
                                       const unsigned* __restrict__ bpacked,
                                       const unsigned char* __restrict__ brow,
                                       unsigned* __restrict__ packed) {
    __shared__ int cur[64];
    int b = blockIdx.x;
    int row0 = b << KB;
    if (threadIdx.x < 64) {
        int rr = row0 + threadIdx.x;
        cur[threadIdx.x] = (rr < NR_TOT) ? row_ptr[rr] : 0;
    }
    __syncthreads();
    int beg = row_ptr[row0];
    int endr = row0 + 64; if (endr > NR_TOT) endr = NR_TOT;
    int end = row_ptr[endr];
    for (int i = beg + threadIdx.x; i < end; i += blockDim.x) {
        int r6 = brow[i];
        unsigned pl = bpacked[i];
        int pos = atomicAdd(&cur[r6], 1);
        packed[pos] = pl;
    }
}

__device__ inline float dec_val(unsigned p) {
    return __uint_as_float((p & 0x7FFFu) << 16);   // exact bf16 -> f32
}

// ---------------------------------------------------------------------------
// Gather SpMM, bf16 source rows (256B/row = wave64 x 4B, one bf16x2/lane).
// ---------------------------------------------------------------------------

// Pass 1: yh[r] = sum v * xh[c]   (rows [0,NU) of combined CSR)
__global__ void spmm_gather_kernel(const int* __restrict__ row_ptr,
                                   const unsigned* __restrict__ packed,
                                   const unsigned* __restrict__ src,  // bf16x2
                                   unsigned* __restrict__ dst) {      // bf16x2
    int r = blockIdx.x * 4 + (threadIdx.x >> 6);
    if (r >= NU) return;
    int lane = threadIdx.x & 63;
    int beg = row_ptr[r], end = row_ptr[r + 1];
    float2 acc = make_float2(0.f, 0.f);
    for (int chunk = beg; chunk < end; chunk += 64) {
        int cn = min(64, end - chunk);
        unsigned pw = (chunk + lane < end) ? packed[chunk + lane] : 0;
        int j = 0;
        for (; j + 1 < cn; j += 2) {
            unsigned p0 = (unsigned)__shfl((int)pw, j);
            unsigned p1 = (unsigned)__shfl((int)pw, j + 1);
            unsigned u0 = src[(p0 >> 15) * 64 + lane];
            unsigned u1 = src[(p1 >> 15) * 64 + lane];
            float v0 = dec_val(p0);
            float v1 = dec_val(p1);
            acc.x += v0 * __uint_as_float(u0 << 16);
            acc.y += v0 * __uint_as_float(u0 & 0xFFFF0000u);
            acc.x += v1 * __uint_as_float(u1 << 16);
            acc.y += v1 * __uint_as_float(u1 & 0xFFFF0000u);
        }
        if (j < cn) {
            unsigned p = (unsigned)__shfl((int)pw, j);
            unsigned u = src[(p >> 15) * 64 + lane];
            float v = dec_val(p);
            acc.x += v * __uint_as_float(u << 16);
            acc.y += v * __uint_as_float(u & 0xFFFF0000u);
        }
    }
    dst[r * 64 + lane] = pack_bf16x2(acc.x, acc.y);
}

// Pass 2 fused: out[r] = sum v * yh[c] - x[r] + e[r]  (rows [NU,NU+NP))
__global__ void spmm_gather_fused_kernel(const int* __restrict__ row_ptr,
                                         const unsigned* __restrict__ packed,
                                         const unsigned* __restrict__ src, // yh
                                         const float* __restrict__ x,
                                         const float* __restrict__ e,
                                         float* __restrict__ out) {
    int r = blockIdx.x * 4 + (threadIdx.x >> 6);
    if (r >= NP) return;
    int lane = threadIdx.x & 63;
    int beg = row_ptr[NU + r], end = row_ptr[NU + r + 1];
    float2 acc = make_float2(0.f, 0.f);
    for (int chunk = beg; chunk < end; chunk += 64) {
        int cn = min(64, end - chunk);
        unsigned pw = (chunk + lane < end) ? packed[chunk + lane] : 0;
        int j = 0;
        for (; j + 1 < cn; j += 2) {
            unsigned p0 = (unsigned)__shfl((int)pw, j);
            unsigned p1 = (unsigned)__shfl((int)pw, j + 1);
            unsigned u0 = src[(p0 >> 15) * 64 + lane];
            unsigned u1 = src[(p1 >> 15) * 64 + lane];
            float v0 = dec_val(p0);
            float v1 = dec_val(p1);
            acc.x += v0 * __uint_as_float(u0 << 16);
            acc.y += v0 * __uint_as_float(u0 & 0xFFFF0000u);
            acc.x += v1 * __uint_as_float(u1 << 16);
            acc.y += v1 * __uint_as_float(u1 & 0xFFFF0000u);
        }
        if (j < cn) {
            unsigned p = (unsigned)__shfl((int)pw, j);
            unsigned u = src[(p >> 15) * 64 + lane];
            float v = dec_val(p);
            acc.x += v * __uint_as_float(u << 16);
            acc.y += v * __uint_as_float(u & 0xFFFF0000u);
        }
    }
    float2 xv = ((const float2*)(x + (size_t)r * DIM))[lane];
    float2 ev = ((const float2*)(e + (size_t)r * DIM))[lane];
    float2 o;
    o.x = acc.x - xv.x + ev.x;
    o.y = acc.y - xv.y + ev.y;
    ((float2*)(out + (size_t)r * DIM))[lane] = o;
}

extern "C" void kernel_launch(void* const* d_in, const int* in_sizes, int n_in,
                              void* d_out, int out_size, void* d_ws, size_t ws_size,
                              hipStream_t stream) {
    // setup_inputs order: t, x, e, vals_up, vals_pu, rows_up, cols_up, rows_pu, cols_pu
    const float* x       = (const float*)d_in[1];
    const float* e       = (const float*)d_in[2];
    const float* vals_up = (const float*)d_in[3];
    const float* vals_pu = (const float*)d_in[4];
    const int*   rows_up = (const int*)d_in[5];
    const int*   cols_up = (const int*)d_in[6];
    const int*   rows_pu = (const int*)d_in[7];
    const int*   cols_pu = (const int*)d_in[8];
    float* out = (float*)d_out;

    // Workspace layout (bytes), total ~53 MB:
    //   yh      : [0, 25,600,000)            NU*64 u32 (bf16x2)
    //     bpacked aliases [0, 12,800,000)    (dead before gather1 writes yh)
    //     brow    aliases [12,800,000, 16,000,000)
    //   xh      : [25,600,000, +12,800,000)  NP*64 u32 (bf16x2)
    //   packed  : [38,400,000, +12,800,000)  2*NNZ u32 pairs (final CSR order)
    //   row_ptr : [51,200,000, +600,004)
    //   bcur    : [51,800,016, +9,376)       NB ints
    //   counts  : [52,400,016, +600,000)
    //   partials: [53,000,016, +1024)
    //   base    : [53,001,040, +1024)
    char* ws = (char*)d_ws;
    unsigned* yh          = (unsigned*)(ws);
    unsigned* bpacked     = (unsigned*)(ws);
    unsigned char* brow   = (unsigned char*)(ws + 12800000);
    unsigned* xh          = (unsigned*)(ws + 25600000);
    unsigned* packed      = (unsigned*)(ws + 38400000);
    int* row_ptr          = (int*)(ws + 51200000);
    int* bcur             = (int*)(ws + 51800016);
    int* counts           = (int*)(ws + 52400016);
    int* partials         = (int*)(ws + 53000016);
    int* scan_base        = (int*)(ws + 53001040);

    const int n  = NR_TOT;                 // 150000 combined rows
    const int nb = (n + 1023) / 1024;      // 147 scan blocks
    const int two_nnz_blocks = (2 * NNZ_C + 255) / 256;

    // x -> bf16 (independent of CSR build)
    cvt_bf16_kernel<<<(NP * 64 + 255) / 256, 256, 0, stream>>>(x, xh, NP * 64);

    // Combined CSR row_ptr
    hipMemsetAsync(counts, 0, (size_t)n * sizeof(int), stream);
    hist_kernel<<<two_nnz_blocks, 256, 0, stream>>>(rows_up, rows_pu, counts);
    block_sum_kernel<<<nb, 1024, 0, stream>>>(counts, partials, n);
    scan_partials_kernel<<<1, 256, 0, stream>>>(partials, scan_base, nb);
    final_scan_kernel<<<nb, 1024, 0, stream>>>(counts, scan_base, row_ptr, n);

    // Two-phase reorder: bucket scatter (L2-resident windows) then finalize
    bucket_cursor_init_kernel<<<(NB + 255) / 256, 256, 0, stream>>>(row_ptr, bcur);
    bucket_scatter_kernel<<<two_nnz_blocks, 256, 0, stream>>>(vals_up, vals_pu,
                                                              rows_up, rows_pu,
                                                              cols_up, cols_pu,
                                                              bcur, bpacked, brow);
    bucket_finalize_kernel<<<NB, 256, 0, stream>>>(row_ptr, bpacked, brow, packed);

    // Pass 1: yh = bf16(HG_up @ xh)   (overwrites bucket staging region)
    spmm_gather_kernel<<<(NU + 3) / 4, 256, 0, stream>>>(row_ptr, packed, xh, yh);

    // Pass 2: out = HG_pu @ yh - x + e
    spmm_gather_fused_kernel<<<(NP + 3) / 4, 256, 0, stream>>>(row_ptr, packed, yh,
                                                               x, e, out);
}

// Round 7
// 411.017 us; speedup vs baseline: 2.4256x; 2.4256x over previous
//
#include <hip/hip_runtime.h>

// Problem constants (match reference setup_inputs)
#define NP 50000     // P: rows of HG_pu / rows of x,e,out
#define NU 100000    // U: rows of HG_up (intermediate y)
#define NNZ_C 1600000
#define NNZ2 (2 * NNZ_C)
#define DIM 128
#define NR_TOT (NU + NP)          // combined rows: [0,NU)=up, [NU,NU+NP)=pu

#define RBSH 7                    // rows per bucket = 128
#define RB 128
#define NBK ((NR_TOT + RB - 1) / RB)   // 1172 buckets
#define ITEMS 8192                // items per partition block
#define IPT (ITEMS / 256)         // 32 items per thread
#define NBLK ((NNZ2 + ITEMS - 1) / ITEMS)  // 391 partition blocks

// round-to-nearest bf16x2 pack: a -> low 16, b -> high 16
__device__ inline unsigned pack_bf16x2(float a, float b) {
    unsigned ia = __float_as_uint(a), ib = __float_as_uint(b);
    ia = (ia + 0x7FFFu + ((ia >> 16) & 1u)) >> 16;
    ib = (ib + 0x7FFFu + ((ib >> 16) & 1u)) >> 16;
    return ia | (ib << 16);
}

__device__ inline float dec_val(unsigned p) {
    return __uint_as_float((p & 0x7FFFu) << 16);   // exact bf16 -> f32
}

// x (fp32 [NP,128]) -> xh (bf16x2 words, 64 per row)
__global__ void cvt_bf16_kernel(const float* __restrict__ x,
                                unsigned* __restrict__ xh, int nwords) {
    int i = blockIdx.x * blockDim.x + threadIdx.x;
    if (i >= nwords) return;
    float2 v = ((const float2*)x)[i];
    xh[i] = pack_bf16x2(v.x, v.y);
}

// ---------------------------------------------------------------------------
// Deterministic two-level partition (radix-style, NO global atomics).
// ---------------------------------------------------------------------------

// Phase 1a: per-block LDS histogram over NBK buckets.
__global__ void p1_hist_kernel(const int* __restrict__ rows_up,
                               const int* __restrict__ rows_pu,
                               int* __restrict__ hist_all) {
    __shared__ int h[NBK];
    for (int k = threadIdx.x; k < NBK; k += 256) h[k] = 0;
    __syncthreads();
    int base = blockIdx.x * ITEMS;
    for (int k = 0; k < IPT; ++k) {
        int i = base + k * 256 + threadIdx.x;
        if (i >= NNZ2) break;
        int r = (i < NNZ_C) ? rows_up[i] : (NU + rows_pu[i - NNZ_C]);
        atomicAdd(&h[r >> RBSH], 1);
    }
    __syncthreads();
    for (int k = threadIdx.x; k < NBK; k += 256)
        hist_all[k * NBLK + blockIdx.x] = h[k];
}

// Phase 1b: one block per bucket, exclusive scan over its NBLK counts.
__global__ void p1_scan_kernel(const int* __restrict__ hist_all,
                               int* __restrict__ base_all,
                               int* __restrict__ totals) {
    __shared__ int lds[512];
    int b = blockIdx.x;
    int v = (threadIdx.x < NBLK) ? hist_all[b * NBLK + threadIdx.x] : 0;
    lds[threadIdx.x] = v;
    __syncthreads();
    for (int off = 1; off < 512; off <<= 1) {
        int t = (threadIdx.x >= (unsigned)off) ? lds[threadIdx.x - off] : 0;
        __syncthreads();
        lds[threadIdx.x] += t;
        __syncthreads();
    }
    if (threadIdx.x < NBLK) base_all[b * NBLK + threadIdx.x] = lds[threadIdx.x] - v;
    if (threadIdx.x == 511) totals[b] = lds[511];
}

// Phase 1c: single block scans NBK bucket totals -> dense bucket bases.
__global__ void bucket_base_scan_kernel(const int* __restrict__ totals,
                                        int* __restrict__ bbase) {
    __shared__ int lds[1024];
    __shared__ int carry;
    if (threadIdx.x == 0) carry = 0;
    __syncthreads();
    for (int start = 0; start < NBK; start += 1024) {
        int i = start + threadIdx.x;
        int v = (i < NBK) ? totals[i] : 0;
        lds[threadIdx.x] = v;
        __syncthreads();
        for (int off = 1; off < 1024; off <<= 1) {
            int t = (threadIdx.x >= (unsigned)off) ? lds[threadIdx.x - off] : 0;
            __syncthreads();
            lds[threadIdx.x] += t;
            __syncthreads();
        }
        if (i < NBK) bbase[i] = carry + lds[threadIdx.x] - v;
        int tot = lds[1023];
        __syncthreads();
        if (threadIdx.x == 0) carry += tot;
        __syncthreads();
    }
    if (threadIdx.x == 0) bbase[NBK] = carry;   // == NNZ2
}

// Phase 1d: scatter into bucket-grouped staging at deterministic positions.
// staging item: {payload u32 = col<<15 | bf16bits(val), row}
__global__ void p1_scatter_kernel(const float* __restrict__ vals_up,
                                  const float* __restrict__ vals_pu,
                                  const int* __restrict__ rows_up,
                                  const int* __restrict__ rows_pu,
                                  const int* __restrict__ cols_up,
                                  const int* __restrict__ cols_pu,
                                  const int* __restrict__ base_all,
                                  const int* __restrict__ bbase,
                                  int2* __restrict__ staging) {
    __shared__ int off[NBK];
    for (int k = threadIdx.x; k < NBK; k += 256) off[k] = 0;
    __syncthreads();
    int base = blockIdx.x * ITEMS;
    for (int k = 0; k < IPT; ++k) {
        int i = base + k * 256 + threadIdx.x;
        if (i >= NNZ2) break;
        int r, c; float v;
        if (i < NNZ_C) { r = rows_up[i]; c = cols_up[i]; v = vals_up[i]; }
        else { int q = i - NNZ_C; r = NU + rows_pu[q]; c = cols_pu[q]; v = vals_pu[q]; }
        int b = r >> RBSH;
        int lp = atomicAdd(&off[b], 1);          // LDS only — fast, low contention
        unsigned vb = __float_as_uint(v);
        unsigned vr = (vb + 0x7FFFu + ((vb >> 16) & 1u)) >> 16;  // bf16 bits, sign=0
        int pos = bbase[b] + base_all[b * NBLK + blockIdx.x] + lp;
        staging[pos] = make_int2((int)(((unsigned)c << 15) | vr), r);
    }
}

// Phase 2: one block per bucket (128 rows). Count rows, local exclusive scan,
// place payloads at final CSR positions (dense ~11 KB window -> L2-resident).
__global__ void p2_finalize_kernel(const int2* __restrict__ staging,
                                   const int* __restrict__ bbase,
                                   unsigned* __restrict__ packed,
                                   int* __restrict__ row_beg,
                                   int* __restrict__ row_cnt) {
    __shared__ int cnt[RB];
    __shared__ int scn[RB];
    __shared__ int cur[RB];
    int b = blockIdx.x;
    int beg = bbase[b], end = bbase[b + 1];
    if (threadIdx.x < RB) cnt[threadIdx.x] = 0;
    __syncthreads();
    for (int i = beg + threadIdx.x; i < end; i += 256)
        atomicAdd(&cnt[staging[i].y & (RB - 1)], 1);
    __syncthreads();
    if (threadIdx.x < RB) scn[threadIdx.x] = cnt[threadIdx.x];
    __syncthreads();
    for (int off = 1; off < RB; off <<= 1) {
        int t = 0;
        if (threadIdx.x < RB && threadIdx.x >= (unsigned)off) t = scn[threadIdx.x - off];
        __syncthreads();
        if (threadIdx.x < RB) scn[threadIdx.x] += t;
        __syncthreads();
    }
    if (threadIdx.x < RB) {
        int excl = scn[threadIdx.x] - cnt[threadIdx.x];
        cur[threadIdx.x] = beg + excl;
        int rr = (b << RBSH) + threadIdx.x;
        if (rr < NR_TOT) { row_beg[rr] = beg + excl; row_cnt[rr] = cnt[threadIdx.x]; }
    }
    __syncthreads();
    for (int i = beg + threadIdx.x; i < end; i += 256) {
        int2 it = staging[i];
        int pos = atomicAdd(&cur[it.y & (RB - 1)], 1);   // LDS only
        packed[pos] = (unsigned)it.x;
    }
}

// ---------------------------------------------------------------------------
// Gather SpMM, bf16 source rows (256B/row = wave64 x 4B, one bf16x2/lane).
// ---------------------------------------------------------------------------

// Pass 1: yh[r] = sum v * xh[c]   (rows [0,NU))
__global__ void spmm_gather_kernel(const int* __restrict__ row_beg,
                                   const int* __restrict__ row_cnt,
                                   const unsigned* __restrict__ packed,
                                   const unsigned* __restrict__ src,  // bf16x2
                                   unsigned* __restrict__ dst) {      // bf16x2
    int r = blockIdx.x * 4 + (threadIdx.x >> 6);
    if (r >= NU) return;
    int lane = threadIdx.x & 63;
    int beg = row_beg[r], end = beg + row_cnt[r];
    float2 acc = make_float2(0.f, 0.f);
    for (int chunk = beg; chunk < end; chunk += 64) {
        int cn = min(64, end - chunk);
        unsigned pw = (chunk + lane < end) ? packed[chunk + lane] : 0;
        int j = 0;
        for (; j + 1 < cn; j += 2) {
            unsigned p0 = (unsigned)__shfl((int)pw, j);
            unsigned p1 = (unsigned)__shfl((int)pw, j + 1);
            unsigned u0 = src[(p0 >> 15) * 64 + lane];
            unsigned u1 = src[(p1 >> 15) * 64 + lane];
            float v0 = dec_val(p0);
            float v1 = dec_val(p1);
            acc.x += v0 * __uint_as_float(u0 << 16);
            acc.y += v0 * __uint_as_float(u0 & 0xFFFF0000u);
            acc.x += v1 * __uint_as_float(u1 << 16);
            acc.y += v1 * __uint_as_float(u1 & 0xFFFF0000u);
        }
        if (j < cn) {
            unsigned p = (unsigned)__shfl((int)pw, j);
            unsigned u = src[(p >> 15) * 64 + lane];
            float v = dec_val(p);
            acc.x += v * __uint_as_float(u << 16);
            acc.y += v * __uint_as_float(u & 0xFFFF0000u);
        }
    }
    dst[r * 64 + lane] = pack_bf16x2(acc.x, acc.y);
}

// Pass 2 fused: out[r] = sum v * yh[c] - x[r] + e[r]  (rows [NU,NU+NP))
__global__ void spmm_gather_fused_kernel(const int* __restrict__ row_beg,
                                         const int* __restrict__ row_cnt,
                                         const unsigned* __restrict__ packed,
                                         const unsigned* __restrict__ src, // yh
                                         const float* __restrict__ x,
                                         const float* __restrict__ e,
                                         float* __restrict__ out) {
    int r = blockIdx.x * 4 + (threadIdx.x >> 6);
    if (r >= NP) return;
    int lane = threadIdx.x & 63;
    int beg = row_beg[NU + r], end = beg + row_cnt[NU + r];
    float2 acc = make_float2(0.f, 0.f);
    for (int chunk = beg; chunk < end; chunk += 64) {
        int cn = min(64, end - chunk);
        unsigned pw = (chunk + lane < end) ? packed[chunk + lane] : 0;
        int j = 0;
        for (; j + 1 < cn; j += 2) {
            unsigned p0 = (unsigned)__shfl((int)pw, j);
            unsigned p1 = (unsigned)__shfl((int)pw, j + 1);
            unsigned u0 = src[(p0 >> 15) * 64 + lane];
            unsigned u1 = src[(p1 >> 15) * 64 + lane];
            float v0 = dec_val(p0);
            float v1 = dec_val(p1);
            acc.x += v0 * __uint_as_float(u0 << 16);
            acc.y += v0 * __uint_as_float(u0 & 0xFFFF0000u);
            acc.x += v1 * __uint_as_float(u1 << 16);
            acc.y += v1 * __uint_as_float(u1 & 0xFFFF0000u);
        }
        if (j < cn) {
            unsigned p = (unsigned)__shfl((int)pw, j);
            unsigned u = src[(p >> 15) * 64 + lane];
            float v = dec_val(p);
            acc.x += v * __uint_as_float(u << 16);
            acc.y += v * __uint_as_float(u & 0xFFFF0000u);
        }
    }
    float2 xv = ((const float2*)(x + (size_t)r * DIM))[lane];
    float2 ev = ((const float2*)(e + (size_t)r * DIM))[lane];
    float2 o;
    o.x = acc.x - xv.x + ev.x;
    o.y = acc.y - xv.y + ev.y;
    ((float2*)(out + (size_t)r * DIM))[lane] = o;
}

extern "C" void kernel_launch(void* const* d_in, const int* in_sizes, int n_in,
                              void* d_out, int out_size, void* d_ws, size_t ws_size,
                              hipStream_t stream) {
    // setup_inputs order: t, x, e, vals_up, vals_pu, rows_up, cols_up, rows_pu, cols_pu
    const float* x       = (const float*)d_in[1];
    const float* e       = (const float*)d_in[2];
    const float* vals_up = (const float*)d_in[3];
    const float* vals_pu = (const float*)d_in[4];
    const int*   rows_up = (const int*)d_in[5];
    const int*   cols_up = (const int*)d_in[6];
    const int*   rows_pu = (const int*)d_in[7];
    const int*   cols_pu = (const int*)d_in[8];
    float* out = (float*)d_out;

    // Workspace layout (bytes), ~56.1 MB total:
    //   yh       : [0, 25,600,000)          NU*64 u32 (bf16x2)
    //     staging aliases [0, 25,600,000)   NNZ2 int2 (dead before gather1)
    //   xh       : [25,600,000, 38,400,000)
    //   packed   : [38,400,000, 51,200,000) NNZ2 u32, final CSR order
    //   hist_all : [51,200,000, +1,833,248) NBK*NBLK ints
    //   base_all : [53,033,248, +1,833,248)
    //   totals   : [54,866,496, +4,688)
    //   bbase    : [54,871,184, +4,692)     NBK+1 ints
    //   row_beg  : [54,875,904, +600,000)
    //   row_cnt  : [55,475,904, +600,000)
    char* ws = (char*)d_ws;
    unsigned* yh     = (unsigned*)(ws);
    int2* staging    = (int2*)(ws);
    unsigned* xh     = (unsigned*)(ws + 25600000);
    unsigned* packed = (unsigned*)(ws + 38400000);
    int* hist_all    = (int*)(ws + 51200000);
    int* base_all    = (int*)(ws + 53033248);
    int* totals      = (int*)(ws + 54866496);
    int* bbase       = (int*)(ws + 54871184);
    int* row_beg     = (int*)(ws + 54875904);
    int* row_cnt     = (int*)(ws + 55475904);

    // x -> bf16 (independent of partition)
    cvt_bf16_kernel<<<(NP * 64 + 255) / 256, 256, 0, stream>>>(x, xh, NP * 64);

    // Deterministic partition -> final CSR (packed + row_beg/row_cnt)
    p1_hist_kernel<<<NBLK, 256, 0, stream>>>(rows_up, rows_pu, hist_all);
    p1_scan_kernel<<<NBK, 512, 0, stream>>>(hist_all, base_all, totals);
    bucket_base_scan_kernel<<<1, 1024, 0, stream>>>(totals, bbase);
    p1_scatter_kernel<<<NBLK, 256, 0, stream>>>(vals_up, vals_pu,
                                                rows_up, rows_pu,
                                                cols_up, cols_pu,
                                                base_all, bbase, staging);
    p2_finalize_kernel<<<NBK, 256, 0, stream>>>(staging, bbase, packed,
                                                row_beg, row_cnt);

    // Pass 1: yh = bf16(HG_up @ xh)   (overwrites staging region)
    spmm_gather_kernel<<<(NU + 3) / 4, 256, 0, stream>>>(row_beg, row_cnt,
                                                         packed, xh, yh);

    // Pass 2: out = HG_pu @ yh - x + e
    spmm_gather_fused_kernel<<<(NP + 3) / 4, 256, 0, stream>>>(row_beg, row_cnt,
                                                               packed, yh,
                                                               x, e, out);
}